// Round 13
// baseline (78.020 us; speedup 1.0000x reference)
//
#include <hip/hip_runtime.h>
#include <math.h>

// TopoBrainPhysical fused forward, round 13: SGPR-STREAM k2 (scalar pipe).
// R12 post-mortem: k2 was LDS-pipe-bound (~30us floor: 192 ds_read_b128/wave
// x 32 waves/CU x ~12cyc on ONE LDS unit/CU). M is wave-uniform -> move the
// operand stream to s_load/K$ (parallel to VALU): one thread owns one whole
// element (all 8 cells, no reduce), weights as SGPR operands in v_fma
// (1-SGPR rule: v_fma(v_h, s_M, v_t)). k2 uses ZERO LDS.
// ws: [0,B*20) elem state | [B*20,+6144) stream: 8 cells x 24 j x 32-float
// records {M[cell][j][0..23], nb1[j], nw1[3][j], nw1[0..2][j], pad3} (fp64
// build) | [+6144,+24) tinit. k1 unchanged from R12 (isolate the change).

#define PI_F 3.14159265358979323846f

typedef float f32x2 __attribute__((ext_vector_type(2)));

__device__ __forceinline__ f32x2 b2(float v) { f32x2 r; r.x = v; r.y = v; return r; }
__device__ __forceinline__ f32x2 pkfma(f32x2 a, f32x2 b, f32x2 c) {
    return __builtin_elementwise_fma(a, b, c);
}

__device__ __forceinline__ float fast_tanh(float v) {
    float e = __expf(2.0f * v);
    return 1.0f - 2.0f * __builtin_amdgcn_rcpf(e + 1.0f);
}

// ===================== kernel 1 (+ appended setup blocks) =====================
// LDS float layout:
// E1P[24][8]@0 (per k: ew1[0..3][k], eb1[k], pad3)   192
// EW2[24][24]@192   EB2[24]@768   EW3T[3][24]@792   EB3[3]@864  -> 880 total
#define K1_LDS 880

extern "C" __global__ void __launch_bounds__(256, 2)
topo_k1(const float* __restrict__ x,
        const float* __restrict__ ew1, const float* __restrict__ eb1,
        const float* __restrict__ ew2, const float* __restrict__ eb2,
        const float* __restrict__ ew3, const float* __restrict__ eb3,
        const float* __restrict__ alog, const float* __restrict__ rlog,
        const float* __restrict__ nw1, const float* __restrict__ nb1,
        const float* __restrict__ nw2, const float* __restrict__ nb2,
        const float* __restrict__ rw1, const float* __restrict__ rb1,
        float* __restrict__ ws, int B)
{
    const int nb1b = (B + 255) >> 8;

    // ---- appended setup blocks: build 32-float records + tinit (fp64) ----
    if ((int)blockIdx.x >= nb1b) {
        const int gid = ((int)blockIdx.x - nb1b) * 256 + (int)threadIdx.x;
        float* M = ws + (size_t)B * 20;
        if (gid < 6144) {
            const int r = gid >> 5, c = gid & 31;
            const int cell = r / 24, j = r - cell * 24;
            float v = 0.0f;
            if (c < 24) {
                double s = 0.0;
                #pragma unroll
                for (int d = 0; d < 12; ++d)
                    s += (double)nw2[j * 12 + d] * (double)rw1[(cell * 12 + d) * 24 + c];
                v = (float)s;
            } else if (c == 24) v = nb1[j];
            else if (c == 25) v = nw1[72 + j];
            else if (c == 26) v = nw1[j];
            else if (c == 27) v = nw1[24 + j];
            else if (c == 28) v = nw1[48 + j];
            M[gid] = v;
        } else if (gid < 6168) {
            const int j2 = gid - 6144;
            double s = (double)rb1[j2];
            for (int i = 0; i < 96; ++i)
                s += (double)nb2[i % 12] * (double)rw1[i * 24 + j2];
            M[6144 + j2] = (float)s;
        }
        return;
    }

    __shared__ float wf[K1_LDS];
    const float4* wq = reinterpret_cast<const float4*>(wf);
    {
        const int tt = threadIdx.x;
        for (int i = tt; i < 24; i += 256) {
            wf[i * 8 + 0] = ew1[i];
            wf[i * 8 + 1] = ew1[24 + i];
            wf[i * 8 + 2] = ew1[48 + i];
            wf[i * 8 + 3] = ew1[72 + i];
            wf[i * 8 + 4] = eb1[i];
        }
        for (int i = tt; i < 576; i += 256) wf[192 + i] = ew2[i];
        for (int i = tt; i < 24;  i += 256) wf[768 + i] = eb2[i];
        for (int i = tt; i < 72;  i += 256) wf[792 + (i % 3) * 24 + (i / 3)] = ew3[i];
        for (int i = tt; i < 3;   i += 256) wf[864 + i] = eb3[i];
    }
    __syncthreads();

    const int b = blockIdx.x * blockDim.x + threadIdx.x;
    if (b >= B) return;

    const float4 xv = *reinterpret_cast<const float4*>(x + (size_t)b * 60 + 56);

    // ---- encoder L1 fused into L2 loop; a2 accumulated packed ----
    f32x2 A2[12];
    #pragma unroll
    for (int c = 0; c < 6; ++c) {
        float4 b4 = wq[192 / 4 + c];
        A2[c*2+0].x = b4.x; A2[c*2+0].y = b4.y;
        A2[c*2+1].x = b4.z; A2[c*2+1].y = b4.w;
    }
    #pragma unroll 2
    for (int k = 0; k < 24; ++k) {
        float4 p  = wq[2 * k];
        float4 p2 = wq[2 * k + 1];
        const float zk = fast_tanh(p2.x + xv.x*p.x + xv.y*p.y + xv.z*p.z + xv.w*p.w);
        const f32x2 zk2 = b2(zk);
        const int rr = 48 + k * 6;
        #pragma unroll
        for (int c = 0; c < 6; ++c) {
            float4 rv = wq[rr + c];
            f32x2 r01; r01.x = rv.x; r01.y = rv.y;
            f32x2 r23; r23.x = rv.z; r23.y = rv.w;
            A2[c*2+0] = pkfma(zk2, r01, A2[c*2+0]);
            A2[c*2+1] = pkfma(zk2, r23, A2[c*2+1]);
        }
    }
    float zt2[24];
    #pragma unroll
    for (int j = 0; j < 24; ++j)
        zt2[j] = fast_tanh((j & 1) ? A2[j >> 1].y : A2[j >> 1].x);

    // ---- encoder L3 ----
    float z0 = wf[864], z1 = wf[865], z2 = wf[866];
    #pragma unroll
    for (int c = 0; c < 6; ++c) {
        float4 v0 = wq[198 + c], v1 = wq[204 + c], v2 = wq[210 + c];
        z0 += zt2[c*4+0]*v0.x + zt2[c*4+1]*v0.y + zt2[c*4+2]*v0.z + zt2[c*4+3]*v0.w;
        z1 += zt2[c*4+0]*v1.x + zt2[c*4+1]*v1.y + zt2[c*4+2]*v1.z + zt2[c*4+3]*v1.w;
        z2 += zt2[c*4+0]*v2.x + zt2[c*4+1]*v2.y + zt2[c*4+2]*v2.z + zt2[c*4+3]*v2.w;
    }

    // ---- normalized adjacency ----
    float ang[4][4];
    {
        float m = fmaxf(fmaxf(alog[0], alog[1]), fmaxf(alog[2], alog[3]));
        float e0 = __expf(alog[0] - m), e1 = __expf(alog[1] - m);
        float e2 = __expf(alog[2] - m), e3 = __expf(alog[3] - m);
        float s = e0 + e1 + e2 + e3;
        float sm[4] = { e0 / s, e1 / s, e2 / s, e3 / s };
        #pragma unroll
        for (int i = 0; i < 4; ++i) {
            const int jn = (i + 3) & 3, jp = (i + 1) & 3;
            float inv = 1.0f / fmaxf(sm[jn] + sm[jp], 1e-6f);
            #pragma unroll
            for (int j = 0; j < 4; ++j) {
                float adj = (j == jn || j == jp) ? 1.0f : 0.0f;
                ang[i][j] = sm[j] * adj * inv;
            }
        }
    }
    float rad[2][2];
    {
        float m = fmaxf(rlog[0], rlog[1]);
        float f0 = __expf(rlog[0] - m), f1 = __expf(rlog[1] - m);
        float fs = f0 + f1;
        float sm0 = f0 / fs, sm1 = f1 / fs;
        rad[0][0] = 0.0f; rad[0][1] = sm1 / fmaxf(sm1, 1e-6f);
        rad[1][1] = 0.0f; rad[1][0] = sm0 / fmaxf(sm0, 1e-6f);
    }

    // ---- bilinear corners ----
    const float r = 1.0f / (1.0f + __expf(-z0));
    const float p = (z1 + PI_F) / (2.0f * PI_F) * 4.0f;
    const float r0f = truncf(r), p0f = truncf(p);
    const float dr = r - r0f, dp = p - p0f;
    const int r0i = (int)r0f, p0i = (int)p0f;

    const float w0c = (1.0f - dr) * (1.0f - dp);
    const float w1c = (1.0f - dr) * dp;
    const float w2c = dr * (1.0f - dp);
    const float w3c = dr * dp;

    const int ri0 = min(r0i, 1);
    const int ri2 = min(r0i + 1, 1);
    const int pi0 = p0i & 3;
    const int pi1 = (p0i + 1) & 3;

    const int c0 = ri0 * 4 + pi0, c1 = ri0 * 4 + pi1;
    const int c2 = ri2 * 4 + pi0, c3 = ri2 * 4 + pi1;

    float cnt[8], wsum[8];
    #pragma unroll
    for (int n = 0; n < 8; ++n) {
        float cm = 0.0f, cw = 0.0f;
        if (c0 == n && w0c > 0.0f) { cm += 1.0f; cw += w0c; }
        if (c1 == n && w1c > 0.0f) { cm += 1.0f; cw += w1c; }
        if (c2 == n && w2c > 0.0f) { cm += 1.0f; cw += w2c; }
        if (c3 == n && w3c > 0.0f) { cm += 1.0f; cw += w3c; }
        cnt[n] = cm; wsum[n] = cw;
    }
    float mc[8], mw[8];
    #pragma unroll
    for (int n = 0; n < 8; ++n) {
        float ac = cnt[n], aw = wsum[n];
        #pragma unroll
        for (int j = 0; j < 4; ++j) {
            const float g = ang[n >> 1][j];
            ac += g * cnt[2 * j + (n & 1)];
            aw += g * wsum[2 * j + (n & 1)];
        }
        #pragma unroll
        for (int j = 0; j < 2; ++j) {
            const float g = rad[n >> 2][j];
            ac += g * cnt[4 * j + (n & 3)];
            aw += g * wsum[4 * j + (n & 3)];
        }
        mc[n] = ac; mw[n] = aw;
    }

    // ---- AoS store: 20 floats per element ----
    float* wp = ws + (size_t)b * 20;
    float4 v0; v0.x = z0;    v0.y = z1;    v0.z = z2;    v0.w = 0.0f;
    float4 v1; v1.x = mc[0]; v1.y = mc[1]; v1.z = mc[2]; v1.w = mc[3];
    float4 v2; v2.x = mc[4]; v2.y = mc[5]; v2.z = mc[6]; v2.w = mc[7];
    float4 v3; v3.x = mw[0]; v3.y = mw[1]; v3.z = mw[2]; v3.w = mw[3];
    float4 v4; v4.x = mw[4]; v4.y = mw[5]; v4.z = mw[6]; v4.w = mw[7];
    reinterpret_cast<float4*>(wp)[0] = v0;
    reinterpret_cast<float4*>(wp)[1] = v1;
    reinterpret_cast<float4*>(wp)[2] = v2;
    reinterpret_cast<float4*>(wp)[3] = v3;
    reinterpret_cast<float4*>(wp)[4] = v4;
}

// ===================== kernel 2: SGPR-stream, zero LDS =====================
// One thread = one element, all 8 cells. All weight reads are wave-uniform
// global loads -> compiler scalarizes to s_load; FMAs use SGPR operands.
extern "C" __global__ void __launch_bounds__(256)
topo_k2(const float* __restrict__ ws,
        const float* __restrict__ rw2, const float* __restrict__ rb2,
        float* __restrict__ out, int B)
{
    const int b = blockIdx.x * blockDim.x + threadIdx.x;
    if (b >= B) return;

    const float* __restrict__ Ms = ws + (size_t)B * 20;
    const float* __restrict__ ti = Ms + 6144;

    // per-element state
    const float* wp = ws + (size_t)b * 20;
    const float4 zv  = reinterpret_cast<const float4*>(wp)[0];
    const float4 mcv0 = reinterpret_cast<const float4*>(wp)[1];
    const float4 mcv1 = reinterpret_cast<const float4*>(wp)[2];
    const float4 mwv0 = reinterpret_cast<const float4*>(wp)[3];
    const float4 mwv1 = reinterpret_cast<const float4*>(wp)[4];
    const float mc[8] = { mcv0.x, mcv0.y, mcv0.z, mcv0.w,
                          mcv1.x, mcv1.y, mcv1.z, mcv1.w };
    const float mw[8] = { mwv0.x, mwv0.y, mwv0.z, mwv0.w,
                          mwv1.x, mwv1.y, mwv1.z, mwv1.w };
    const float z0 = zv.x, z1 = zv.y, z2 = zv.z;

    float t[24];
    #pragma unroll
    for (int k = 0; k < 24; ++k) t[k] = ti[k];   // uniform -> s_load broadcast

    #pragma unroll
    for (int cell = 0; cell < 8; ++cell) {
        const float mcc = mc[cell], mwc = mw[cell];
        const float* __restrict__ rc = Ms + cell * 768;   // 24 recs x 32 floats
        #pragma unroll 1
        for (int j = 0; j < 24; ++j) {
            const float* __restrict__ rec = rc + (j << 5);
            const float q = z0 * rec[26] + z1 * rec[27] + z2 * rec[28];
            const float h = fast_tanh(rec[24] + mcc * q + mwc * rec[25]);
            #pragma unroll
            for (int k = 0; k < 24; ++k) t[k] = fmaf(h, rec[k], t[k]);
        }
    }

    // ---- readout layer 2 (uniform weights -> s_load) ----
    float o0 = rb2[0], o1 = rb2[1], o2 = rb2[2], o3 = rb2[3];
    #pragma unroll
    for (int j = 0; j < 24; ++j) {
        const float tt = fast_tanh(t[j]);
        o0 = fmaf(tt, rw2[j * 4 + 0], o0);
        o1 = fmaf(tt, rw2[j * 4 + 1], o1);
        o2 = fmaf(tt, rw2[j * 4 + 2], o2);
        o3 = fmaf(tt, rw2[j * 4 + 3], o3);
    }
    float4 ov; ov.x = o0; ov.y = o1; ov.z = o2; ov.w = o3;
    *reinterpret_cast<float4*>(out + (size_t)b * 4) = ov;
}

// ===================== fallback fused kernel =====================
extern "C" __global__ void __launch_bounds__(256, 2)
topo_fused(const float* __restrict__ x,
           const float* __restrict__ ew1, const float* __restrict__ eb1,
           const float* __restrict__ ew2, const float* __restrict__ eb2,
           const float* __restrict__ ew3, const float* __restrict__ eb3,
           const float* __restrict__ nw1, const float* __restrict__ nb1,
           const float* __restrict__ nw2, const float* __restrict__ nb2,
           const float* __restrict__ alog, const float* __restrict__ rlog,
           const float* __restrict__ rw1, const float* __restrict__ rb1,
           const float* __restrict__ rw2, const float* __restrict__ rb2,
           float* __restrict__ out, int B)
{
    const int b = blockIdx.x * blockDim.x + threadIdx.x;
    if (b >= B) return;

    float ang[4][4];
    {
        float m = fmaxf(fmaxf(alog[0], alog[1]), fmaxf(alog[2], alog[3]));
        float e0 = __expf(alog[0] - m), e1 = __expf(alog[1] - m);
        float e2 = __expf(alog[2] - m), e3 = __expf(alog[3] - m);
        float s = e0 + e1 + e2 + e3;
        float sm[4] = { e0 / s, e1 / s, e2 / s, e3 / s };
        #pragma unroll
        for (int i = 0; i < 4; ++i) {
            const int jn = (i + 3) & 3, jp = (i + 1) & 3;
            float inv = 1.0f / fmaxf(sm[jn] + sm[jp], 1e-6f);
            #pragma unroll
            for (int j = 0; j < 4; ++j) {
                float adj = (j == jn || j == jp) ? 1.0f : 0.0f;
                ang[i][j] = sm[j] * adj * inv;
            }
        }
    }
    float rad[2][2];
    {
        float m = fmaxf(rlog[0], rlog[1]);
        float f0 = __expf(rlog[0] - m), f1 = __expf(rlog[1] - m);
        float fs = f0 + f1;
        float sm0 = f0 / fs, sm1 = f1 / fs;
        rad[0][0] = 0.0f; rad[0][1] = sm1 / fmaxf(sm1, 1e-6f);
        rad[1][1] = 0.0f; rad[1][0] = sm0 / fmaxf(sm0, 1e-6f);
    }

    const float4 xv = *reinterpret_cast<const float4*>(x + (size_t)b * 60 + 56);
    float zt[24];
    #pragma unroll
    for (int j = 0; j < 24; ++j) {
        float a = eb1[j];
        a += xv.x * ew1[j];
        a += xv.y * ew1[24 + j];
        a += xv.z * ew1[48 + j];
        a += xv.w * ew1[72 + j];
        zt[j] = fast_tanh(a);
    }
    float z0 = eb3[0], z1 = eb3[1], z2 = eb3[2];
    #pragma unroll
    for (int j = 0; j < 24; ++j) {
        float a = eb2[j];
        #pragma unroll
        for (int k = 0; k < 24; ++k) a += zt[k] * ew2[k * 24 + j];
        const float z2t = fast_tanh(a);
        z0 += z2t * ew3[j * 3 + 0];
        z1 += z2t * ew3[j * 3 + 1];
        z2 += z2t * ew3[j * 3 + 2];
    }

    const float r = 1.0f / (1.0f + __expf(-z0));
    const float p = (z1 + PI_F) / (2.0f * PI_F) * 4.0f;
    const float r0f = truncf(r), p0f = truncf(p);
    const float dr = r - r0f, dp = p - p0f;
    const int r0i = (int)r0f, p0i = (int)p0f;
    const float w0c = (1.0f - dr) * (1.0f - dp);
    const float w1c = (1.0f - dr) * dp;
    const float w2c = dr * (1.0f - dp);
    const float w3c = dr * dp;
    const int ri0 = min(r0i, 1);
    const int ri2 = min(r0i + 1, 1);
    const int pi0 = p0i & 3;
    const int pi1 = (p0i + 1) & 3;
    const int c0 = ri0 * 4 + pi0, c1 = ri0 * 4 + pi1;
    const int c2 = ri2 * 4 + pi0, c3 = ri2 * 4 + pi1;

    float cnt[8], wsum[8];
    #pragma unroll
    for (int n = 0; n < 8; ++n) {
        float cm = 0.0f, cw = 0.0f;
        if (c0 == n && w0c > 0.0f) { cm += 1.0f; cw += w0c; }
        if (c1 == n && w1c > 0.0f) { cm += 1.0f; cw += w1c; }
        if (c2 == n && w2c > 0.0f) { cm += 1.0f; cw += w2c; }
        if (c3 == n && w3c > 0.0f) { cm += 1.0f; cw += w3c; }
        cnt[n] = cm; wsum[n] = cw;
    }
    float mc[8], mw[8];
    #pragma unroll
    for (int n = 0; n < 8; ++n) {
        float ac = cnt[n], aw = wsum[n];
        #pragma unroll
        for (int j = 0; j < 4; ++j) {
            const float g = ang[n >> 1][j];
            ac += g * cnt[2 * j + (n & 1)];
            aw += g * wsum[2 * j + (n & 1)];
        }
        #pragma unroll
        for (int j = 0; j < 2; ++j) {
            const float g = rad[n >> 2][j];
            ac += g * cnt[4 * j + (n & 3)];
            aw += g * wsum[4 * j + (n & 3)];
        }
        mc[n] = ac; mw[n] = aw;
    }

    float t[24];
    #pragma unroll
    for (int j = 0; j < 24; ++j) t[j] = rb1[j];
    #pragma unroll
    for (int n = 0; n < 8; ++n) {
        const float f0 = mc[n] * z0, f1 = mc[n] * z1, f2 = mc[n] * z2;
        float ho[12];
        #pragma unroll
        for (int d = 0; d < 12; ++d) ho[d] = nb2[d];
        #pragma unroll
        for (int j = 0; j < 24; ++j) {
            const float hj = fast_tanh(nb1[j] + f0 * nw1[j] + f1 * nw1[24 + j]
                                       + f2 * nw1[48 + j] + mw[n] * nw1[72 + j]);
            #pragma unroll
            for (int d = 0; d < 12; ++d) ho[d] += hj * nw2[j * 12 + d];
        }
        #pragma unroll
        for (int d = 0; d < 12; ++d) {
            const int rbase = (n * 12 + d) * 24;
            #pragma unroll
            for (int j2 = 0; j2 < 24; ++j2) t[j2] += ho[d] * rw1[rbase + j2];
        }
    }

    float o0 = rb2[0], o1 = rb2[1], o2 = rb2[2], o3 = rb2[3];
    #pragma unroll
    for (int j = 0; j < 24; ++j) {
        const float tt = fast_tanh(t[j]);
        o0 += tt * rw2[j * 4 + 0];
        o1 += tt * rw2[j * 4 + 1];
        o2 += tt * rw2[j * 4 + 2];
        o3 += tt * rw2[j * 4 + 3];
    }
    float4 ov; ov.x = o0; ov.y = o1; ov.z = o2; ov.w = o3;
    *reinterpret_cast<float4*>(out + (size_t)b * 4) = ov;
}

extern "C" void kernel_launch(void* const* d_in, const int* in_sizes, int n_in,
                              void* d_out, int out_size, void* d_ws, size_t ws_size,
                              hipStream_t stream) {
    const float* x    = (const float*)d_in[0];
    const float* ew1  = (const float*)d_in[1];
    const float* eb1  = (const float*)d_in[2];
    const float* ew2  = (const float*)d_in[3];
    const float* eb2  = (const float*)d_in[4];
    const float* ew3  = (const float*)d_in[5];
    const float* eb3  = (const float*)d_in[6];
    const float* nw1  = (const float*)d_in[7];
    const float* nb1  = (const float*)d_in[8];
    const float* nw2  = (const float*)d_in[9];
    const float* nb2  = (const float*)d_in[10];
    const float* alog = (const float*)d_in[11];
    const float* rlog = (const float*)d_in[12];
    const float* rw1  = (const float*)d_in[13];
    const float* rb1  = (const float*)d_in[14];
    const float* rw2  = (const float*)d_in[15];
    const float* rb2  = (const float*)d_in[16];
    float* out = (float*)d_out;

    const int B = in_sizes[0] / 60;   // x is (B, 15, 4)
    const size_t ws_needed = ((size_t)B * 20 + 6168) * sizeof(float);

    if (ws_size >= ws_needed) {
        float* ws = (float*)d_ws;
        const int nb1b = (B + 255) / 256;
        const int g1 = nb1b + 25;                 // + setup blocks (6168 entries)
        topo_k1<<<g1, 256, 0, stream>>>(x, ew1, eb1, ew2, eb2, ew3, eb3,
                                        alog, rlog, nw1, nb1, nw2, nb2,
                                        rw1, rb1, ws, B);
        const int g2 = (B + 255) / 256;
        topo_k2<<<g2, 256, 0, stream>>>(ws, rw2, rb2, out, B);
    } else {
        const int g = (B + 255) / 256;
        topo_fused<<<g, 256, 0, stream>>>(
            x, ew1, eb1, ew2, eb2, ew3, eb3, nw1, nb1, nw2, nb2,
            alog, rlog, rw1, rb1, rw2, rb2, out, B);
    }
}

// Round 14
// 50.734 us; speedup vs baseline: 1.5378x; 1.5378x over previous
//
#include <hip/hip_runtime.h>
#include <math.h>

// TopoBrainPhysical fused forward, round 14: E=4 elements/thread in k2.
// Cross-round model: k2 is LDS-pipe-bound (~12cyc per ds_read_b128, one LDS
// unit/CU shared by 32 waves). R12 (E=2) = 37us. E=4 halves LDS instr/elem
// again: 8 reads/iter (2 pk + 6 M) feed 4 elements' accumulation.
// T[48]+state[28] ~95 live regs -> __launch_bounds__(256,4) caps VGPR at 128
// (4 waves/SIMD = exactly the 4096-wave grid; no occupancy loss).
// R13's scalar-stream k2 (65us, SMEM-latency-bound) reverted.
// k1 unchanged from R12. M built in fp64 (absmax margin).

#define PI_F 3.14159265358979323846f

typedef float f32x2 __attribute__((ext_vector_type(2)));

__device__ __forceinline__ f32x2 b2(float v) { f32x2 r; r.x = v; r.y = v; return r; }
__device__ __forceinline__ f32x2 mk2(float a, float b) { f32x2 r; r.x = a; r.y = b; return r; }
__device__ __forceinline__ f32x2 pkfma(f32x2 a, f32x2 b, f32x2 c) {
    return __builtin_elementwise_fma(a, b, c);
}

__device__ __forceinline__ float fast_tanh(float v) {
    float e = __expf(2.0f * v);
    return 1.0f - 2.0f * __builtin_amdgcn_rcpf(e + 1.0f);
}

__device__ __forceinline__ f32x2 tanh2(f32x2 v) {
    f32x2 e; e.x = __expf(2.0f * v.x); e.y = __expf(2.0f * v.y);
    f32x2 ep = e + b2(1.0f);
    f32x2 r; r.x = __builtin_amdgcn_rcpf(ep.x); r.y = __builtin_amdgcn_rcpf(ep.y);
    return pkfma(b2(-2.0f), r, b2(1.0f));
}

// butterfly sum over the 4 lanes of a quad; all lanes get the total.
__device__ __forceinline__ float quad_sum(float x) {
    x += __int_as_float(__builtin_amdgcn_update_dpp(
             0, __float_as_int(x), 0xB1, 0xF, 0xF, true)); // {1,0,3,2}
    x += __int_as_float(__builtin_amdgcn_update_dpp(
             0, __float_as_int(x), 0x4E, 0xF, 0xF, true)); // {2,3,0,1}
    return x;
}

// add value from lane^4 (ds_swizzle xor mode)
__device__ __forceinline__ float xor4_sum(float x) {
    return x + __int_as_float(
        __builtin_amdgcn_ds_swizzle(__float_as_int(x), 0x101F));
}

// ===================== kernel 1 (+ appended setup blocks) =====================
// LDS float layout:
// E1P[24][8]@0 (per k: ew1[0..3][k], eb1[k], pad3)   192
// EW2[24][24]@192   EB2[24]@768   EW3T[3][24]@792   EB3[3]@864  -> 880 total
#define K1_LDS 880
// ws layout: [0, B*20)  per-element {z(4), mc(8), mw(8)}  (AoS)
//            [B*20, +4608) M_cell[8][24][24]   [+4608, +4632) tinit[24]

extern "C" __global__ void __launch_bounds__(256, 2)
topo_k1(const float* __restrict__ x,
        const float* __restrict__ ew1, const float* __restrict__ eb1,
        const float* __restrict__ ew2, const float* __restrict__ eb2,
        const float* __restrict__ ew3, const float* __restrict__ eb3,
        const float* __restrict__ alog, const float* __restrict__ rlog,
        const float* __restrict__ nw2, const float* __restrict__ nb2,
        const float* __restrict__ rw1, const float* __restrict__ rb1,
        float* __restrict__ ws, int B)
{
    const int nb1b = (B + 255) >> 8;

    // ---- appended setup blocks: build M_cell and tinit (fp64) ----
    if ((int)blockIdx.x >= nb1b) {
        const int gid = ((int)blockIdx.x - nb1b) * 256 + (int)threadIdx.x;
        float* M = ws + (size_t)B * 20;
        if (gid < 4608) {
            const int cell = gid / 576, rem = gid - cell * 576;
            const int j = rem / 24, j2 = rem - j * 24;
            double s = 0.0;
            #pragma unroll
            for (int d = 0; d < 12; ++d)
                s += (double)nw2[j * 12 + d] * (double)rw1[(cell * 12 + d) * 24 + j2];
            M[gid] = (float)s;
        } else if (gid < 4632) {
            const int j2 = gid - 4608;
            double s = (double)rb1[j2];
            for (int i = 0; i < 96; ++i)
                s += (double)nb2[i % 12] * (double)rw1[i * 24 + j2];
            M[4608 + j2] = (float)s;
        }
        return;
    }

    __shared__ float wf[K1_LDS];
    const float4* wq = reinterpret_cast<const float4*>(wf);
    {
        const int tt = threadIdx.x;
        for (int i = tt; i < 24; i += 256) {
            wf[i * 8 + 0] = ew1[i];
            wf[i * 8 + 1] = ew1[24 + i];
            wf[i * 8 + 2] = ew1[48 + i];
            wf[i * 8 + 3] = ew1[72 + i];
            wf[i * 8 + 4] = eb1[i];
        }
        for (int i = tt; i < 576; i += 256) wf[192 + i] = ew2[i];
        for (int i = tt; i < 24;  i += 256) wf[768 + i] = eb2[i];
        for (int i = tt; i < 72;  i += 256) wf[792 + (i % 3) * 24 + (i / 3)] = ew3[i];
        for (int i = tt; i < 3;   i += 256) wf[864 + i] = eb3[i];
    }
    __syncthreads();

    const int b = blockIdx.x * blockDim.x + threadIdx.x;
    if (b >= B) return;

    const float4 xv = *reinterpret_cast<const float4*>(x + (size_t)b * 60 + 56);

    // ---- encoder L1 fused into L2 loop; a2 accumulated packed ----
    f32x2 A2[12];
    #pragma unroll
    for (int c = 0; c < 6; ++c) {
        float4 b4 = wq[192 / 4 + c];
        A2[c*2+0].x = b4.x; A2[c*2+0].y = b4.y;
        A2[c*2+1].x = b4.z; A2[c*2+1].y = b4.w;
    }
    #pragma unroll 2
    for (int k = 0; k < 24; ++k) {
        float4 p  = wq[2 * k];
        float4 p2 = wq[2 * k + 1];
        const float zk = fast_tanh(p2.x + xv.x*p.x + xv.y*p.y + xv.z*p.z + xv.w*p.w);
        const f32x2 zk2 = b2(zk);
        const int rr = 48 + k * 6;
        #pragma unroll
        for (int c = 0; c < 6; ++c) {
            float4 rv = wq[rr + c];
            A2[c*2+0] = pkfma(zk2, mk2(rv.x, rv.y), A2[c*2+0]);
            A2[c*2+1] = pkfma(zk2, mk2(rv.z, rv.w), A2[c*2+1]);
        }
    }
    float zt2[24];
    #pragma unroll
    for (int j = 0; j < 24; ++j)
        zt2[j] = fast_tanh((j & 1) ? A2[j >> 1].y : A2[j >> 1].x);

    // ---- encoder L3 ----
    float z0 = wf[864], z1 = wf[865], z2 = wf[866];
    #pragma unroll
    for (int c = 0; c < 6; ++c) {
        float4 v0 = wq[198 + c], v1 = wq[204 + c], v2 = wq[210 + c];
        z0 += zt2[c*4+0]*v0.x + zt2[c*4+1]*v0.y + zt2[c*4+2]*v0.z + zt2[c*4+3]*v0.w;
        z1 += zt2[c*4+0]*v1.x + zt2[c*4+1]*v1.y + zt2[c*4+2]*v1.z + zt2[c*4+3]*v1.w;
        z2 += zt2[c*4+0]*v2.x + zt2[c*4+1]*v2.y + zt2[c*4+2]*v2.z + zt2[c*4+3]*v2.w;
    }

    // ---- normalized adjacency ----
    float ang[4][4];
    {
        float m = fmaxf(fmaxf(alog[0], alog[1]), fmaxf(alog[2], alog[3]));
        float e0 = __expf(alog[0] - m), e1 = __expf(alog[1] - m);
        float e2 = __expf(alog[2] - m), e3 = __expf(alog[3] - m);
        float s = e0 + e1 + e2 + e3;
        float sm[4] = { e0 / s, e1 / s, e2 / s, e3 / s };
        #pragma unroll
        for (int i = 0; i < 4; ++i) {
            const int jn = (i + 3) & 3, jp = (i + 1) & 3;
            float inv = 1.0f / fmaxf(sm[jn] + sm[jp], 1e-6f);
            #pragma unroll
            for (int j = 0; j < 4; ++j) {
                float adj = (j == jn || j == jp) ? 1.0f : 0.0f;
                ang[i][j] = sm[j] * adj * inv;
            }
        }
    }
    float rad[2][2];
    {
        float m = fmaxf(rlog[0], rlog[1]);
        float f0 = __expf(rlog[0] - m), f1 = __expf(rlog[1] - m);
        float fs = f0 + f1;
        float sm0 = f0 / fs, sm1 = f1 / fs;
        rad[0][0] = 0.0f; rad[0][1] = sm1 / fmaxf(sm1, 1e-6f);
        rad[1][1] = 0.0f; rad[1][0] = sm0 / fmaxf(sm0, 1e-6f);
    }

    // ---- bilinear corners ----
    const float r = 1.0f / (1.0f + __expf(-z0));
    const float p = (z1 + PI_F) / (2.0f * PI_F) * 4.0f;
    const float r0f = truncf(r), p0f = truncf(p);
    const float dr = r - r0f, dp = p - p0f;
    const int r0i = (int)r0f, p0i = (int)p0f;

    const float w0c = (1.0f - dr) * (1.0f - dp);
    const float w1c = (1.0f - dr) * dp;
    const float w2c = dr * (1.0f - dp);
    const float w3c = dr * dp;

    const int ri0 = min(r0i, 1);
    const int ri2 = min(r0i + 1, 1);
    const int pi0 = p0i & 3;
    const int pi1 = (p0i + 1) & 3;

    const int c0 = ri0 * 4 + pi0, c1 = ri0 * 4 + pi1;
    const int c2 = ri2 * 4 + pi0, c3 = ri2 * 4 + pi1;

    float cnt[8], wsum[8];
    #pragma unroll
    for (int n = 0; n < 8; ++n) {
        float cm = 0.0f, cw = 0.0f;
        if (c0 == n && w0c > 0.0f) { cm += 1.0f; cw += w0c; }
        if (c1 == n && w1c > 0.0f) { cm += 1.0f; cw += w1c; }
        if (c2 == n && w2c > 0.0f) { cm += 1.0f; cw += w2c; }
        if (c3 == n && w3c > 0.0f) { cm += 1.0f; cw += w3c; }
        cnt[n] = cm; wsum[n] = cw;
    }
    float mc[8], mw[8];
    #pragma unroll
    for (int n = 0; n < 8; ++n) {
        float ac = cnt[n], aw = wsum[n];
        #pragma unroll
        for (int j = 0; j < 4; ++j) {
            const float g = ang[n >> 1][j];
            ac += g * cnt[2 * j + (n & 1)];
            aw += g * wsum[2 * j + (n & 1)];
        }
        #pragma unroll
        for (int j = 0; j < 2; ++j) {
            const float g = rad[n >> 2][j];
            ac += g * cnt[4 * j + (n & 3)];
            aw += g * wsum[4 * j + (n & 3)];
        }
        mc[n] = ac; mw[n] = aw;
    }

    // ---- AoS store: 20 floats per element ----
    float* wp = ws + (size_t)b * 20;
    float4 v0; v0.x = z0;    v0.y = z1;    v0.z = z2;    v0.w = 0.0f;
    float4 v1; v1.x = mc[0]; v1.y = mc[1]; v1.z = mc[2]; v1.w = mc[3];
    float4 v2; v2.x = mc[4]; v2.y = mc[5]; v2.z = mc[6]; v2.w = mc[7];
    float4 v3; v3.x = mw[0]; v3.y = mw[1]; v3.z = mw[2]; v3.w = mw[3];
    float4 v4; v4.x = mw[4]; v4.y = mw[5]; v4.z = mw[6]; v4.w = mw[7];
    reinterpret_cast<float4*>(wp)[0] = v0;
    reinterpret_cast<float4*>(wp)[1] = v1;
    reinterpret_cast<float4*>(wp)[2] = v2;
    reinterpret_cast<float4*>(wp)[3] = v3;
    reinterpret_cast<float4*>(wp)[4] = v4;
}

// ===================== kernel 2: E=4 elements/thread =====================
// LDS float layout (R12-identical):
// PK[24][8]@0 (nw1[0..3][j], nb1[j], pad3)                 192
// M: 8 cells, stride 580 (24x24 row-major + pad) @192      4640
// tinit[24]@4832  RW2[24][4]@4856  RB2[4]@4952  -> 4956 floats (19.8KB)
// Lane map: cp = tid&3 (cells 2cp,2cp+1), half = (tid>>2)&1 (12 outputs),
// slot = tid>>3 -> elements 4*slot .. 4*slot+3.
#define K2_LDS 4956

extern "C" __global__ void __launch_bounds__(256, 4)
topo_k2(const float* __restrict__ ws,
        const float* __restrict__ nw1, const float* __restrict__ nb1,
        const float* __restrict__ rw2, const float* __restrict__ rb2,
        float* __restrict__ out, int B)
{
    __shared__ float wf[K2_LDS];
    const float4* wq = reinterpret_cast<const float4*>(wf);
    {
        const int tt = threadIdx.x;
        const float* Msrc = ws + (size_t)B * 20;
        for (int i = tt; i < 4608; i += 256) {
            const int cell = i / 576, rem = i - cell * 576;
            wf[192 + cell * 580 + rem] = Msrc[i];
        }
        for (int i = tt; i < 24; i += 256) wf[4832 + i] = Msrc[4608 + i];
        for (int i = tt; i < 24; i += 256) {
            wf[i * 8 + 0] = nw1[i];
            wf[i * 8 + 1] = nw1[24 + i];
            wf[i * 8 + 2] = nw1[48 + i];
            wf[i * 8 + 3] = nw1[72 + i];
            wf[i * 8 + 4] = nb1[i];
        }
        for (int i = tt; i < 96; i += 256) wf[4856 + i] = rw2[i];
        for (int i = tt; i < 4;  i += 256) wf[4952 + i] = rb2[i];
    }
    __syncthreads();

    const int tid  = blockIdx.x * blockDim.x + threadIdx.x;
    const int cp   = tid & 3;
    const int half = (tid >> 2) & 1;
    const int slot = tid >> 3;
    const int nS   = (B + 3) >> 2;
    if (slot >= nS) return;
    const int e0 = 4 * slot;
    const int eA = e0;
    const int eB = (e0 + 1 < B) ? e0 + 1 : B - 1;
    const int eC = (e0 + 2 < B) ? e0 + 2 : B - 1;
    const int eD = (e0 + 3 < B) ? e0 + 3 : B - 1;

    // per-element state, packed across element pairs {A,B} and {C,D}
    const float* wpA = ws + (size_t)eA * 20;
    const float* wpB = ws + (size_t)eB * 20;
    const float* wpC = ws + (size_t)eC * 20;
    const float* wpD = ws + (size_t)eD * 20;
    const float4 zA = reinterpret_cast<const float4*>(wpA)[0];
    const float4 zB = reinterpret_cast<const float4*>(wpB)[0];
    const float4 zC = reinterpret_cast<const float4*>(wpC)[0];
    const float4 zD = reinterpret_cast<const float4*>(wpD)[0];
    const float2 mcA2 = *reinterpret_cast<const float2*>(wpA + 4 + 2 * cp);
    const float2 mwA2 = *reinterpret_cast<const float2*>(wpA + 12 + 2 * cp);
    const float2 mcB2 = *reinterpret_cast<const float2*>(wpB + 4 + 2 * cp);
    const float2 mwB2 = *reinterpret_cast<const float2*>(wpB + 12 + 2 * cp);
    const float2 mcC2 = *reinterpret_cast<const float2*>(wpC + 4 + 2 * cp);
    const float2 mwC2 = *reinterpret_cast<const float2*>(wpC + 12 + 2 * cp);
    const float2 mcD2 = *reinterpret_cast<const float2*>(wpD + 4 + 2 * cp);
    const float2 mwD2 = *reinterpret_cast<const float2*>(wpD + 12 + 2 * cp);

    const f32x2 ZX01 = mk2(zA.x, zB.x), ZX23 = mk2(zC.x, zD.x);
    const f32x2 ZY01 = mk2(zA.y, zB.y), ZY23 = mk2(zC.y, zD.y);
    const f32x2 ZZ01 = mk2(zA.z, zB.z), ZZ23 = mk2(zC.z, zD.z);
    const f32x2 MCA01 = mk2(mcA2.x, mcB2.x), MCA23 = mk2(mcC2.x, mcD2.x);
    const f32x2 MCB01 = mk2(mcA2.y, mcB2.y), MCB23 = mk2(mcC2.y, mcD2.y);
    const f32x2 MWA01 = mk2(mwA2.x, mwB2.x), MWA23 = mk2(mwC2.x, mwD2.x);
    const f32x2 MWB01 = mk2(mwA2.y, mwB2.y), MWB23 = mk2(mwC2.y, mwD2.y);

    // M float4 bases: cellA=2cp, cellB=2cp+1; stride 145 float4; half*3 offset
    const int mA = 48 + (2 * cp) * 145 + half * 3;
    const int mB = mA + 145;

    // T[elem][6]: 12 outputs packed as 6 f32x2 per element
    f32x2 T0[6], T1[6], T2[6], T3[6];
    #pragma unroll
    for (int k = 0; k < 6; ++k) {
        T0[k] = b2(0.0f); T1[k] = b2(0.0f);
        T2[k] = b2(0.0f); T3[k] = b2(0.0f);
    }

    #pragma unroll 1
    for (int j = 0; j < 24; ++j) {
        float4 pk  = wq[2 * j];
        float4 pk2 = wq[2 * j + 1];
        const f32x2 PX = b2(pk.x), PY = b2(pk.y), PZ = b2(pk.z);
        const f32x2 PW = b2(pk.w), NB = b2(pk2.x);
        f32x2 Q01 = pkfma(ZZ01, PZ, pkfma(ZY01, PY, ZX01 * PX));
        f32x2 Q23 = pkfma(ZZ23, PZ, pkfma(ZY23, PY, ZX23 * PX));
        f32x2 HA01 = tanh2(pkfma(MCA01, Q01, pkfma(MWA01, PW, NB)));
        f32x2 HA23 = tanh2(pkfma(MCA23, Q23, pkfma(MWA23, PW, NB)));
        f32x2 HB01 = tanh2(pkfma(MCB01, Q01, pkfma(MWB01, PW, NB)));
        f32x2 HB23 = tanh2(pkfma(MCB23, Q23, pkfma(MWB23, PW, NB)));

        const int ra = mA + j * 6, rb = mB + j * 6;
        float4 a0 = wq[ra], a1 = wq[ra + 1], a2v = wq[ra + 2];
        float4 bb0 = wq[rb], bb1 = wq[rb + 1], bb2 = wq[rb + 2];
        const f32x2 A0 = mk2(a0.x, a0.y),  A1 = mk2(a0.z, a0.w);
        const f32x2 A2 = mk2(a1.x, a1.y),  A3 = mk2(a1.z, a1.w);
        const f32x2 A4 = mk2(a2v.x, a2v.y), A5 = mk2(a2v.z, a2v.w);
        const f32x2 B0 = mk2(bb0.x, bb0.y), B1 = mk2(bb0.z, bb0.w);
        const f32x2 B2 = mk2(bb1.x, bb1.y), B3 = mk2(bb1.z, bb1.w);
        const f32x2 B4 = mk2(bb2.x, bb2.y), B5 = mk2(bb2.z, bb2.w);

        f32x2 h;
        h = b2(HA01.x);
        T0[0]=pkfma(h,A0,T0[0]); T0[1]=pkfma(h,A1,T0[1]); T0[2]=pkfma(h,A2,T0[2]);
        T0[3]=pkfma(h,A3,T0[3]); T0[4]=pkfma(h,A4,T0[4]); T0[5]=pkfma(h,A5,T0[5]);
        h = b2(HB01.x);
        T0[0]=pkfma(h,B0,T0[0]); T0[1]=pkfma(h,B1,T0[1]); T0[2]=pkfma(h,B2,T0[2]);
        T0[3]=pkfma(h,B3,T0[3]); T0[4]=pkfma(h,B4,T0[4]); T0[5]=pkfma(h,B5,T0[5]);
        h = b2(HA01.y);
        T1[0]=pkfma(h,A0,T1[0]); T1[1]=pkfma(h,A1,T1[1]); T1[2]=pkfma(h,A2,T1[2]);
        T1[3]=pkfma(h,A3,T1[3]); T1[4]=pkfma(h,A4,T1[4]); T1[5]=pkfma(h,A5,T1[5]);
        h = b2(HB01.y);
        T1[0]=pkfma(h,B0,T1[0]); T1[1]=pkfma(h,B1,T1[1]); T1[2]=pkfma(h,B2,T1[2]);
        T1[3]=pkfma(h,B3,T1[3]); T1[4]=pkfma(h,B4,T1[4]); T1[5]=pkfma(h,B5,T1[5]);
        h = b2(HA23.x);
        T2[0]=pkfma(h,A0,T2[0]); T2[1]=pkfma(h,A1,T2[1]); T2[2]=pkfma(h,A2,T2[2]);
        T2[3]=pkfma(h,A3,T2[3]); T2[4]=pkfma(h,A4,T2[4]); T2[5]=pkfma(h,A5,T2[5]);
        h = b2(HB23.x);
        T2[0]=pkfma(h,B0,T2[0]); T2[1]=pkfma(h,B1,T2[1]); T2[2]=pkfma(h,B2,T2[2]);
        T2[3]=pkfma(h,B3,T2[3]); T2[4]=pkfma(h,B4,T2[4]); T2[5]=pkfma(h,B5,T2[5]);
        h = b2(HA23.y);
        T3[0]=pkfma(h,A0,T3[0]); T3[1]=pkfma(h,A1,T3[1]); T3[2]=pkfma(h,A2,T3[2]);
        T3[3]=pkfma(h,A3,T3[3]); T3[4]=pkfma(h,A4,T3[4]); T3[5]=pkfma(h,A5,T3[5]);
        h = b2(HB23.y);
        T3[0]=pkfma(h,B0,T3[0]); T3[1]=pkfma(h,B1,T3[1]); T3[2]=pkfma(h,B2,T3[2]);
        T3[3]=pkfma(h,B3,T3[3]); T3[4]=pkfma(h,B4,T3[4]); T3[5]=pkfma(h,B5,T3[5]);
    }

    // ---- reduce over cellpairs (quad butterfly); add tinit(half) ----
    float t0[12], t1[12], t2[12], t3[12];
    #pragma unroll
    for (int k = 0; k < 12; ++k) {
        const float a = (k & 1) ? T0[k >> 1].y : T0[k >> 1].x;
        const float b = (k & 1) ? T1[k >> 1].y : T1[k >> 1].x;
        const float c = (k & 1) ? T2[k >> 1].y : T2[k >> 1].x;
        const float d = (k & 1) ? T3[k >> 1].y : T3[k >> 1].x;
        t0[k] = quad_sum(a); t1[k] = quad_sum(b);
        t2[k] = quad_sum(c); t3[k] = quad_sum(d);
    }
    #pragma unroll
    for (int c = 0; c < 3; ++c) {
        float4 ti = wq[1208 + half * 3 + c];
        t0[c*4+0] += ti.x; t0[c*4+1] += ti.y; t0[c*4+2] += ti.z; t0[c*4+3] += ti.w;
        t1[c*4+0] += ti.x; t1[c*4+1] += ti.y; t1[c*4+2] += ti.z; t1[c*4+3] += ti.w;
        t2[c*4+0] += ti.x; t2[c*4+1] += ti.y; t2[c*4+2] += ti.z; t2[c*4+3] += ti.w;
        t3[c*4+0] += ti.x; t3[c*4+1] += ti.y; t3[c*4+2] += ti.z; t3[c*4+3] += ti.w;
    }

    // ---- readout layer 2: partial over this half's 12 rows ----
    float o0[4] = {0,0,0,0}, o1[4] = {0,0,0,0}, o2[4] = {0,0,0,0}, o3[4] = {0,0,0,0};
    #pragma unroll
    for (int k = 0; k < 12; ++k) {
        float4 rv = wq[1214 + half * 12 + k];
        const float v0 = fast_tanh(t0[k]);
        const float v1 = fast_tanh(t1[k]);
        const float v2 = fast_tanh(t2[k]);
        const float v3 = fast_tanh(t3[k]);
        o0[0] += v0*rv.x; o0[1] += v0*rv.y; o0[2] += v0*rv.z; o0[3] += v0*rv.w;
        o1[0] += v1*rv.x; o1[1] += v1*rv.y; o1[2] += v1*rv.z; o1[3] += v1*rv.w;
        o2[0] += v2*rv.x; o2[1] += v2*rv.y; o2[2] += v2*rv.z; o2[3] += v2*rv.w;
        o3[0] += v3*rv.x; o3[1] += v3*rv.y; o3[2] += v3*rv.z; o3[3] += v3*rv.w;
    }
    #pragma unroll
    for (int d = 0; d < 4; ++d) {
        o0[d] = xor4_sum(o0[d]); o1[d] = xor4_sum(o1[d]);
        o2[d] = xor4_sum(o2[d]); o3[d] = xor4_sum(o3[d]);
    }

    if ((tid & 7) == 0) {
        float4 ob = wq[1238];
        float4 ov;
        ov.x = o0[0] + ob.x; ov.y = o0[1] + ob.y;
        ov.z = o0[2] + ob.z; ov.w = o0[3] + ob.w;
        *reinterpret_cast<float4*>(out + (size_t)e0 * 4) = ov;
        if (e0 + 1 < B) {
            ov.x = o1[0] + ob.x; ov.y = o1[1] + ob.y;
            ov.z = o1[2] + ob.z; ov.w = o1[3] + ob.w;
            *reinterpret_cast<float4*>(out + (size_t)(e0 + 1) * 4) = ov;
        }
        if (e0 + 2 < B) {
            ov.x = o2[0] + ob.x; ov.y = o2[1] + ob.y;
            ov.z = o2[2] + ob.z; ov.w = o2[3] + ob.w;
            *reinterpret_cast<float4*>(out + (size_t)(e0 + 2) * 4) = ov;
        }
        if (e0 + 3 < B) {
            ov.x = o3[0] + ob.x; ov.y = o3[1] + ob.y;
            ov.z = o3[2] + ob.z; ov.w = o3[3] + ob.w;
            *reinterpret_cast<float4*>(out + (size_t)(e0 + 3) * 4) = ov;
        }
    }
}

// ===================== fallback fused kernel =====================
extern "C" __global__ void __launch_bounds__(256, 2)
topo_fused(const float* __restrict__ x,
           const float* __restrict__ ew1, const float* __restrict__ eb1,
           const float* __restrict__ ew2, const float* __restrict__ eb2,
           const float* __restrict__ ew3, const float* __restrict__ eb3,
           const float* __restrict__ nw1, const float* __restrict__ nb1,
           const float* __restrict__ nw2, const float* __restrict__ nb2,
           const float* __restrict__ alog, const float* __restrict__ rlog,
           const float* __restrict__ rw1, const float* __restrict__ rb1,
           const float* __restrict__ rw2, const float* __restrict__ rb2,
           float* __restrict__ out, int B)
{
    const int b = blockIdx.x * blockDim.x + threadIdx.x;
    if (b >= B) return;

    float ang[4][4];
    {
        float m = fmaxf(fmaxf(alog[0], alog[1]), fmaxf(alog[2], alog[3]));
        float e0 = __expf(alog[0] - m), e1 = __expf(alog[1] - m);
        float e2 = __expf(alog[2] - m), e3 = __expf(alog[3] - m);
        float s = e0 + e1 + e2 + e3;
        float sm[4] = { e0 / s, e1 / s, e2 / s, e3 / s };
        #pragma unroll
        for (int i = 0; i < 4; ++i) {
            const int jn = (i + 3) & 3, jp = (i + 1) & 3;
            float inv = 1.0f / fmaxf(sm[jn] + sm[jp], 1e-6f);
            #pragma unroll
            for (int j = 0; j < 4; ++j) {
                float adj = (j == jn || j == jp) ? 1.0f : 0.0f;
                ang[i][j] = sm[j] * adj * inv;
            }
        }
    }
    float rad[2][2];
    {
        float m = fmaxf(rlog[0], rlog[1]);
        float f0 = __expf(rlog[0] - m), f1 = __expf(rlog[1] - m);
        float fs = f0 + f1;
        float sm0 = f0 / fs, sm1 = f1 / fs;
        rad[0][0] = 0.0f; rad[0][1] = sm1 / fmaxf(sm1, 1e-6f);
        rad[1][1] = 0.0f; rad[1][0] = sm0 / fmaxf(sm0, 1e-6f);
    }

    const float4 xv = *reinterpret_cast<const float4*>(x + (size_t)b * 60 + 56);
    float zt[24];
    #pragma unroll
    for (int j = 0; j < 24; ++j) {
        float a = eb1[j];
        a += xv.x * ew1[j];
        a += xv.y * ew1[24 + j];
        a += xv.z * ew1[48 + j];
        a += xv.w * ew1[72 + j];
        zt[j] = fast_tanh(a);
    }
    float z0 = eb3[0], z1 = eb3[1], z2 = eb3[2];
    #pragma unroll
    for (int j = 0; j < 24; ++j) {
        float a = eb2[j];
        #pragma unroll
        for (int k = 0; k < 24; ++k) a += zt[k] * ew2[k * 24 + j];
        const float z2t = fast_tanh(a);
        z0 += z2t * ew3[j * 3 + 0];
        z1 += z2t * ew3[j * 3 + 1];
        z2 += z2t * ew3[j * 3 + 2];
    }

    const float r = 1.0f / (1.0f + __expf(-z0));
    const float p = (z1 + PI_F) / (2.0f * PI_F) * 4.0f;
    const float r0f = truncf(r), p0f = truncf(p);
    const float dr = r - r0f, dp = p - p0f;
    const int r0i = (int)r0f, p0i = (int)p0f;
    const float w0c = (1.0f - dr) * (1.0f - dp);
    const float w1c = (1.0f - dr) * dp;
    const float w2c = dr * (1.0f - dp);
    const float w3c = dr * dp;
    const int ri0 = min(r0i, 1);
    const int ri2 = min(r0i + 1, 1);
    const int pi0 = p0i & 3;
    const int pi1 = (p0i + 1) & 3;
    const int c0 = ri0 * 4 + pi0, c1 = ri0 * 4 + pi1;
    const int c2 = ri2 * 4 + pi0, c3 = ri2 * 4 + pi1;

    float cnt[8], wsum[8];
    #pragma unroll
    for (int n = 0; n < 8; ++n) {
        float cm = 0.0f, cw = 0.0f;
        if (c0 == n && w0c > 0.0f) { cm += 1.0f; cw += w0c; }
        if (c1 == n && w1c > 0.0f) { cm += 1.0f; cw += w1c; }
        if (c2 == n && w2c > 0.0f) { cm += 1.0f; cw += w2c; }
        if (c3 == n && w3c > 0.0f) { cm += 1.0f; cw += w3c; }
        cnt[n] = cm; wsum[n] = cw;
    }
    float mc[8], mw[8];
    #pragma unroll
    for (int n = 0; n < 8; ++n) {
        float ac = cnt[n], aw = wsum[n];
        #pragma unroll
        for (int j = 0; j < 4; ++j) {
            const float g = ang[n >> 1][j];
            ac += g * cnt[2 * j + (n & 1)];
            aw += g * wsum[2 * j + (n & 1)];
        }
        #pragma unroll
        for (int j = 0; j < 2; ++j) {
            const float g = rad[n >> 2][j];
            ac += g * cnt[4 * j + (n & 3)];
            aw += g * wsum[4 * j + (n & 3)];
        }
        mc[n] = ac; mw[n] = aw;
    }

    float t[24];
    #pragma unroll
    for (int j = 0; j < 24; ++j) t[j] = rb1[j];
    #pragma unroll
    for (int n = 0; n < 8; ++n) {
        const float f0 = mc[n] * z0, f1 = mc[n] * z1, f2 = mc[n] * z2;
        float ho[12];
        #pragma unroll
        for (int d = 0; d < 12; ++d) ho[d] = nb2[d];
        #pragma unroll
        for (int j = 0; j < 24; ++j) {
            const float hj = fast_tanh(nb1[j] + f0 * nw1[j] + f1 * nw1[24 + j]
                                       + f2 * nw1[48 + j] + mw[n] * nw1[72 + j]);
            #pragma unroll
            for (int d = 0; d < 12; ++d) ho[d] += hj * nw2[j * 12 + d];
        }
        #pragma unroll
        for (int d = 0; d < 12; ++d) {
            const int rbase = (n * 12 + d) * 24;
            #pragma unroll
            for (int j2 = 0; j2 < 24; ++j2) t[j2] += ho[d] * rw1[rbase + j2];
        }
    }

    float o0 = rb2[0], o1 = rb2[1], o2 = rb2[2], o3 = rb2[3];
    #pragma unroll
    for (int j = 0; j < 24; ++j) {
        const float tt = fast_tanh(t[j]);
        o0 += tt * rw2[j * 4 + 0];
        o1 += tt * rw2[j * 4 + 1];
        o2 += tt * rw2[j * 4 + 2];
        o3 += tt * rw2[j * 4 + 3];
    }
    float4 ov; ov.x = o0; ov.y = o1; ov.z = o2; ov.w = o3;
    *reinterpret_cast<float4*>(out + (size_t)b * 4) = ov;
}

extern "C" void kernel_launch(void* const* d_in, const int* in_sizes, int n_in,
                              void* d_out, int out_size, void* d_ws, size_t ws_size,
                              hipStream_t stream) {
    const float* x    = (const float*)d_in[0];
    const float* ew1  = (const float*)d_in[1];
    const float* eb1  = (const float*)d_in[2];
    const float* ew2  = (const float*)d_in[3];
    const float* eb2  = (const float*)d_in[4];
    const float* ew3  = (const float*)d_in[5];
    const float* eb3  = (const float*)d_in[6];
    const float* nw1  = (const float*)d_in[7];
    const float* nb1  = (const float*)d_in[8];
    const float* nw2  = (const float*)d_in[9];
    const float* nb2  = (const float*)d_in[10];
    const float* alog = (const float*)d_in[11];
    const float* rlog = (const float*)d_in[12];
    const float* rw1  = (const float*)d_in[13];
    const float* rb1  = (const float*)d_in[14];
    const float* rw2  = (const float*)d_in[15];
    const float* rb2  = (const float*)d_in[16];
    float* out = (float*)d_out;

    const int B = in_sizes[0] / 60;   // x is (B, 15, 4)
    const size_t ws_needed = ((size_t)B * 20 + 4632) * sizeof(float);

    if (ws_size >= ws_needed) {
        float* ws = (float*)d_ws;
        const int nb1b = (B + 255) / 256;
        const int g1 = nb1b + 19;                 // + setup blocks (4632 entries)
        topo_k1<<<g1, 256, 0, stream>>>(x, ew1, eb1, ew2, eb2, ew3, eb3,
                                        alog, rlog, nw2, nb2, rw1, rb1, ws, B);
        const long long nS = ((long long)B + 3) / 4;
        const long long tot2 = nS * 8;
        const int g2 = (int)((tot2 + 255) / 256);
        topo_k2<<<g2, 256, 0, stream>>>(ws, nw1, nb1, rw2, rb2, out, B);
    } else {
        const int g = (B + 255) / 256;
        topo_fused<<<g, 256, 0, stream>>>(
            x, ew1, eb1, ew2, eb2, ew3, eb3, nw1, nb1, nw2, nb2,
            alog, rlog, rw1, rb1, rw2, rb2, out, B);
    }
}